// Round 1
// baseline (298.161 us; speedup 1.0000x reference)
//
#include <hip/hip_runtime.h>
#include <cstdint>
#include <cstddef>

#define FMIN_F (-3.402823466e38f)

__device__ __forceinline__ float wave_sum(float v) {
#pragma unroll
    for (int off = 32; off > 0; off >>= 1)
        v += __shfl_down(v, off, 64);
    return v; // valid in lane 0
}

// y[mi][b][r] = dot(X[b,:], W_mi[r,:]) + B_mi[r]   (times scale0 for mi==0)
// Each wave computes 4 consecutive rows for all 4 batches.
// Block = 256 threads = 4 waves = 16 rows. Grid = NMAT*4096/16 blocks.
template <int NMAT>
__global__ __launch_bounds__(256) void gemv_kernel(
    const float* __restrict__ X,                                  // [4][4096]
    const float* __restrict__ W0, const float* __restrict__ B0,
    const float* __restrict__ W1, const float* __restrict__ B1,
    const float* __restrict__ W2, const float* __restrict__ B2,
    float scale0,
    float* __restrict__ Y)                                        // [NMAT][4][4096]
{
    const int wave = threadIdx.x >> 6;
    const int lane = threadIdx.x & 63;
    const int rid  = blockIdx.x * 16 + wave * 4;       // global row id
    const int mi   = (NMAT == 1) ? 0 : (rid >> 12);    // matrix index
    const int r    = rid & 4095;

    const float* W  = (mi == 0) ? W0 : (mi == 1) ? W1 : W2;
    const float* Bs = (mi == 0) ? B0 : (mi == 1) ? B1 : B2;
    const float4* W4 = (const float4*)W + (size_t)r * 1024;
    const float4* X4 = (const float4*)X;

    float acc[4][4] = {{0.f, 0.f, 0.f, 0.f}};
    for (int it = 0; it < 16; ++it) {
        const int idx = it * 64 + lane;                // float4 index within row
        const float4 x0 = X4[idx];
        const float4 x1 = X4[1024 + idx];
        const float4 x2 = X4[2048 + idx];
        const float4 x3 = X4[3072 + idx];
#pragma unroll
        for (int j = 0; j < 4; ++j) {
            const float4 w = W4[(size_t)j * 1024 + idx];
            acc[j][0] += w.x * x0.x + w.y * x0.y + w.z * x0.z + w.w * x0.w;
            acc[j][1] += w.x * x1.x + w.y * x1.y + w.z * x1.z + w.w * x1.w;
            acc[j][2] += w.x * x2.x + w.y * x2.y + w.z * x2.z + w.w * x2.w;
            acc[j][3] += w.x * x3.x + w.y * x3.y + w.z * x3.z + w.w * x3.w;
        }
    }
#pragma unroll
    for (int j = 0; j < 4; ++j) {
#pragma unroll
        for (int b = 0; b < 4; ++b) {
            float v = wave_sum(acc[j][b]);
            if (lane == 0) {
                float o = v + Bs[r + j];
                if (mi == 0) o *= scale0;
                Y[((size_t)(mi * 4 + b)) * 4096 + (r + j)] = o;
            }
        }
    }
}

// One block (256 thr) per head bh in [0,128).
// Only the CAM-active columns (sinks [0,SB] and recent [PAST-RB, S)) are
// computed; everything else is exactly fmin in the reference -> softmax 0.
__global__ __launch_bounds__(256) void attn_kernel(
    const float* __restrict__ qkv,     // [3][4][4096] : q (pre-scaled), k_new, v_new
    const float* __restrict__ pk,      // [B,H,2048,128]
    const float* __restrict__ pv,      // [B,H,2048,128]
    const float* __restrict__ amask,   // [B,1,1,2049]
    const float* __restrict__ cam,     // [B*H,1,2049]
    const float* __restrict__ ps,      // [B*H,2048]
    const int* __restrict__ sbp,
    const int* __restrict__ rbp,
    float* __restrict__ attn_out)      // [4][4096]
{
    constexpr int PAST = 2048;
    constexpr int S    = 2049;
    constexpr int HD   = 128;
    const int bh = blockIdx.x;
    const int b  = bh >> 5;
    const int h  = bh & 31;
    const int SB = sbp[0];
    const int RB = rbp[0];
    const int NS = SB + 1;              // sink count (cols 0..SB)
    const int NA = NS + RB + 1;         // + recent count (cols PAST-RB .. PAST)

    __shared__ float s_c[512];          // scores -> probabilities -> coefficients
    __shared__ float s_red[256];
    __shared__ float s_mm;              // merge_mask / MERGE

    const int tid  = threadIdx.x;
    const int wave = tid >> 6;
    const int lane = tid & 63;

    const float* qh   = qkv + (size_t)b * 4096 + h * HD;
    const float* knew = qkv + (size_t)(4 + b) * 4096 + h * HD;
    const float* vnew = qkv + (size_t)(8 + b) * 4096 + h * HD;

    const float2 ql = ((const float2*)qh)[lane];

    // ---- scores over the active set (one row per wave-iteration) ----
    for (int i = wave; i < NA; i += 4) {
        const int s = (i < NS) ? i : (PAST - RB + (i - NS));
        const float2* kr = (s < PAST)
            ? (const float2*)(pk + ((size_t)bh * PAST + s) * HD)
            : (const float2*)knew;
        const float2 kk = kr[lane];
        float p = ql.x * kk.x + ql.y * kk.y;
        p = wave_sum(p);
        if (lane == 0) {
            const float m  = cam[(size_t)bh * S + s];
            float sc = fmaxf(p + amask[(size_t)b * S + s], FMIN_F);
            sc = sc * m + (1.0f - m) * FMIN_F;
            s_c[i] = sc;
        }
    }

    // ---- mean_attn over ps[:SB] and ps[PAST-RB:PAST] -> merge mask ----
    {
        float part = 0.0f;
        const int cnt = SB + RB;
        for (int i = tid; i < cnt; i += 256) {
            const int idx = (i < SB) ? i : (PAST - RB + (i - SB));
            part += ps[(size_t)bh * PAST + idx];
        }
        s_red[tid] = part;
    }
    __syncthreads();   // also makes s_c score writes visible
#pragma unroll
    for (int st = 128; st > 0; st >>= 1) {
        if (tid < st) s_red[tid] += s_red[tid + st];
        __syncthreads();
    }
    if (tid == 0) {
        const float mean = s_red[0] / (float)(SB + RB);
        const float prob = ps[(size_t)bh * PAST + (PAST - RB)] / mean;
        s_mm = (prob > 1.0f) ? (1.0f / 32.0f) : 0.0f;
    }
    __syncthreads();

    // ---- softmax over the NA active scores ----
    float mx = -INFINITY;
    for (int i = tid; i < NA; i += 256) mx = fmaxf(mx, s_c[i]);
    s_red[tid] = mx;
    __syncthreads();
#pragma unroll
    for (int st = 128; st > 0; st >>= 1) {
        if (tid < st) s_red[tid] = fmaxf(s_red[tid], s_red[tid + st]);
        __syncthreads();
    }
    const float gmax = s_red[0];
    __syncthreads();

    float lsum = 0.0f;
    for (int i = tid; i < NA; i += 256) {
        const float e = expf(s_c[i] - gmax);
        s_c[i] = e;
        lsum += e;
    }
    s_red[tid] = lsum;
    __syncthreads();
#pragma unroll
    for (int st = 128; st > 0; st >>= 1) {
        if (tid < st) s_red[tid] += s_red[tid + st];
        __syncthreads();
    }
    const float inv = 1.0f / s_red[0];
    __syncthreads();
    for (int i = tid; i < NA; i += 256) s_c[i] *= inv;
    __syncthreads();

    // ---- fold CAM value-merge + pinned column into coefficients ----
    // c[i(s=PAST-RB)] += mm/MERGE * sum_{s=PAST-RB+1..+MERGE} aw[s]
    // c[i(s=SB)]       = 1.0(pinned) * 0.99(v scale) = 0.99
    if (tid == 0) {
        float sm = 0.0f;
#pragma unroll
        for (int j = 1; j <= 32; ++j) sm += s_c[NS + j];
        s_c[NS] += s_mm * sm;
        s_c[SB]  = 0.99f;
    }
    __syncthreads();

    // ---- PV: out[d] = sum_i c[i] * v[s(i)][d] ----
    const int d     = tid & 127;
    const int halfq = tid >> 7;
    float acc = 0.0f;
    for (int i = halfq; i < NA; i += 2) {
        const int s = (i < NS) ? i : (PAST - RB + (i - NS));
        const float* vr = (s < PAST)
            ? (pv + ((size_t)bh * PAST + s) * HD)
            : vnew;
        acc += s_c[i] * vr[d];
    }
    s_red[tid] = acc;
    __syncthreads();
    if (tid < 128)
        attn_out[(size_t)b * 4096 + h * HD + d] = s_red[tid] + s_red[tid + 128];
}

extern "C" void kernel_launch(void* const* d_in, const int* in_sizes, int n_in,
                              void* d_out, int out_size, void* d_ws, size_t ws_size,
                              hipStream_t stream)
{
    const float* hs = (const float*)d_in[0];   // hidden_states [4,1,4096]
    const float* pk = (const float*)d_in[1];   // past_key  [4,32,2048,128]
    const float* pv = (const float*)d_in[2];   // past_value[4,32,2048,128]
    const float* am = (const float*)d_in[3];   // attention_mask [4,1,1,2049]
    const float* cm = (const float*)d_in[4];   // attn_masks_next [128,1,2049]
    const float* ps = (const float*)d_in[5];   // previous_scores [128,2048]
    const float* Wq = (const float*)d_in[6];
    const float* bq = (const float*)d_in[7];
    const float* Wk = (const float*)d_in[8];
    const float* bk = (const float*)d_in[9];
    const float* Wv = (const float*)d_in[10];
    const float* bv = (const float*)d_in[11];
    const float* Wo = (const float*)d_in[12];
    const float* bo = (const float*)d_in[13];
    const int*   sb = (const int*)d_in[14];
    const int*   rb = (const int*)d_in[15];

    float* qkv  = (float*)d_ws;                // 3*4*4096 floats
    float* aout = qkv + 3 * 4 * 4096;          // 4*4096 floats
    float* out  = (float*)d_out;               // [4,1,4096] fp32

    const float scaling = 0.08838834764831845f;   // 128^-0.5

    gemv_kernel<3><<<768, 256, 0, stream>>>(hs, Wq, bq, Wk, bk, Wv, bv, scaling, qkv);
    attn_kernel<<<128, 256, 0, stream>>>(qkv, pk, pv, am, cm, ps, sb, rb, aout);
    gemv_kernel<1><<<256, 256, 0, stream>>>(aout, Wo, bo, Wo, bo, Wo, bo, 1.0f, out);
}

// Round 2
// 153.348 us; speedup vs baseline: 1.9443x; 1.9443x over previous
//
#include <hip/hip_runtime.h>
#include <cstdint>
#include <cstddef>

#define FMIN_F (-3.402823466e38f)

__device__ __forceinline__ float wave_sum(float v) {
#pragma unroll
    for (int off = 32; off > 0; off >>= 1)
        v += __shfl_down(v, off, 64);
    return v; // valid in lane 0
}

// ---------------- GEMV (unchanged from R1) ----------------
template <int NMAT>
__global__ __launch_bounds__(256) void gemv_kernel(
    const float* __restrict__ X,
    const float* __restrict__ W0, const float* __restrict__ B0,
    const float* __restrict__ W1, const float* __restrict__ B1,
    const float* __restrict__ W2, const float* __restrict__ B2,
    float scale0,
    float* __restrict__ Y)
{
    const int wave = threadIdx.x >> 6;
    const int lane = threadIdx.x & 63;
    const int rid  = blockIdx.x * 16 + wave * 4;
    const int mi   = (NMAT == 1) ? 0 : (rid >> 12);
    const int r    = rid & 4095;

    const float* W  = (mi == 0) ? W0 : (mi == 1) ? W1 : W2;
    const float* Bs = (mi == 0) ? B0 : (mi == 1) ? B1 : B2;
    const float4* W4 = (const float4*)W + (size_t)r * 1024;
    const float4* X4 = (const float4*)X;

    float acc[4][4] = {{0.f, 0.f, 0.f, 0.f}};
    for (int it = 0; it < 16; ++it) {
        const int idx = it * 64 + lane;
        const float4 x0 = X4[idx];
        const float4 x1 = X4[1024 + idx];
        const float4 x2 = X4[2048 + idx];
        const float4 x3 = X4[3072 + idx];
#pragma unroll
        for (int j = 0; j < 4; ++j) {
            const float4 w = W4[(size_t)j * 1024 + idx];
            acc[j][0] += w.x * x0.x + w.y * x0.y + w.z * x0.z + w.w * x0.w;
            acc[j][1] += w.x * x1.x + w.y * x1.y + w.z * x1.z + w.w * x1.w;
            acc[j][2] += w.x * x2.x + w.y * x2.y + w.z * x2.z + w.w * x2.w;
            acc[j][3] += w.x * x3.x + w.y * x3.y + w.z * x3.z + w.w * x3.w;
        }
    }
#pragma unroll
    for (int j = 0; j < 4; ++j) {
#pragma unroll
        for (int b = 0; b < 4; ++b) {
            float v = wave_sum(acc[j][b]);
            if (lane == 0) {
                float o = v + Bs[r + j];
                if (mi == 0) o *= scale0;
                Y[((size_t)(mi * 4 + b)) * 4096 + (r + j)] = o;
            }
        }
    }
}

// ---------------- Attention phase 1: scores ----------------
// grid (16 chunks, 128 heads), block 256 (4 waves). Wave computes one
// active column's q.k per iteration, 8 columns per wave.
__global__ __launch_bounds__(256) void score_kernel(
    const float* __restrict__ qkv,     // [3][4][4096]
    const float* __restrict__ pk,      // [B,H,2048,128]
    const float* __restrict__ amask,   // [B,1,1,2049]
    const float* __restrict__ cam,     // [B*H,1,2049]
    const int* __restrict__ sbp, const int* __restrict__ rbp,
    float* __restrict__ scores)        // [128][512]
{
    constexpr int PAST = 2048, S = 2049, HD = 128;
    const int bh = blockIdx.y;
    const int b  = bh >> 5;
    const int h  = bh & 31;
    const int SB = sbp[0], RB = rbp[0];
    const int NS = SB + 1;
    const int NA = NS + RB + 1;

    const int wave = threadIdx.x >> 6;
    const int lane = threadIdx.x & 63;

    const float* qh   = qkv + (size_t)b * 4096 + h * HD;
    const float* knew = qkv + (size_t)(4 + b) * 4096 + h * HD;
    const float2 ql = ((const float2*)qh)[lane];

#pragma unroll
    for (int j = 0; j < 8; ++j) {
        const int i = blockIdx.x * 32 + j * 4 + wave;
        if (i >= NA) continue;
        const int s = (i < NS) ? i : (PAST - RB + (i - NS));
        const float2* kr = (s < PAST)
            ? (const float2*)(pk + ((size_t)bh * PAST + s) * HD)
            : (const float2*)knew;
        const float2 kk = kr[lane];
        float p = ql.x * kk.x + ql.y * kk.y;
        p = wave_sum(p);
        if (lane == 0) {
            const float m  = cam[(size_t)bh * S + s];
            float sc = fmaxf(p + amask[(size_t)b * S + s], FMIN_F);
            sc = sc * m + (1.0f - m) * FMIN_F;
            scores[(size_t)bh * 512 + i] = sc;
        }
    }
}

// ---------------- Attention phase 2: softmax + coefficient fixups ----------------
// grid 128, block 256. In-place scores -> coefficients.
__global__ __launch_bounds__(256) void softmax_kernel(
    const float* __restrict__ ps,      // [B*H,2048]
    const int* __restrict__ sbp, const int* __restrict__ rbp,
    float* __restrict__ scores)        // [128][512] in/out
{
    constexpr int PAST = 2048;
    const int bh = blockIdx.x;
    const int SB = sbp[0], RB = rbp[0];
    const int NS = SB + 1;
    const int NA = NS + RB + 1;
    const int tid = threadIdx.x;

    __shared__ float s_c[512];
    __shared__ float s_red[256];
    __shared__ float s_mm;

    for (int i = tid; i < NA; i += 256) s_c[i] = scores[(size_t)bh * 512 + i];

    // mean over ps[:SB] and ps[PAST-RB:PAST]
    {
        float part = 0.0f;
        const int cnt = SB + RB;
        for (int i = tid; i < cnt; i += 256) {
            const int idx = (i < SB) ? i : (PAST - RB + (i - SB));
            part += ps[(size_t)bh * PAST + idx];
        }
        s_red[tid] = part;
    }
    __syncthreads();
#pragma unroll
    for (int st = 128; st > 0; st >>= 1) {
        if (tid < st) s_red[tid] += s_red[tid + st];
        __syncthreads();
    }
    if (tid == 0) {
        const float mean = s_red[0] / (float)(SB + RB);
        const float prob = ps[(size_t)bh * PAST + (PAST - RB)] / mean;
        s_mm = (prob > 1.0f) ? (1.0f / 32.0f) : 0.0f;
    }
    __syncthreads();

    float mx = -INFINITY;
    for (int i = tid; i < NA; i += 256) mx = fmaxf(mx, s_c[i]);
    s_red[tid] = mx;
    __syncthreads();
#pragma unroll
    for (int st = 128; st > 0; st >>= 1) {
        if (tid < st) s_red[tid] = fmaxf(s_red[tid], s_red[tid + st]);
        __syncthreads();
    }
    const float gmax = s_red[0];
    __syncthreads();

    float lsum = 0.0f;
    for (int i = tid; i < NA; i += 256) {
        const float e = expf(s_c[i] - gmax);
        s_c[i] = e;
        lsum += e;
    }
    s_red[tid] = lsum;
    __syncthreads();
#pragma unroll
    for (int st = 128; st > 0; st >>= 1) {
        if (tid < st) s_red[tid] += s_red[tid + st];
        __syncthreads();
    }
    const float inv = 1.0f / s_red[0];
    __syncthreads();
    for (int i = tid; i < NA; i += 256) s_c[i] *= inv;
    __syncthreads();

    if (tid == 0) {
        float sm = 0.0f;
#pragma unroll
        for (int j = 1; j <= 32; ++j) sm += s_c[NS + j];
        s_c[NS] += s_mm * sm;       // folded CAM value-merge
        s_c[SB]  = 0.99f;           // pinned col * 0.99 value scale
    }
    __syncthreads();

    for (int i = tid; i < NA; i += 256) scores[(size_t)bh * 512 + i] = s_c[i];
}

// ---------------- Attention phase 3: PV partials ----------------
// grid (8 chunks, 128 heads), block 256. Each block: ~NA/8 columns, all 128 dims.
__global__ __launch_bounds__(256) void pv_kernel(
    const float* __restrict__ qkv,     // for v_new
    const float* __restrict__ pv,      // [B,H,2048,128]
    const float* __restrict__ coeff,   // [128][512]
    const int* __restrict__ sbp, const int* __restrict__ rbp,
    float* __restrict__ partial)       // [128][8][128]
{
    constexpr int PAST = 2048, HD = 128;
    const int bh = blockIdx.y;
    const int b  = bh >> 5;
    const int h  = bh & 31;
    const int SB = sbp[0], RB = rbp[0];
    const int NS = SB + 1;
    const int NA = NS + RB + 1;
    const int CPC = (NA + 7) >> 3;               // columns per chunk
    const int i0 = blockIdx.x * CPC;
    const int i1 = min(NA, i0 + CPC);

    const int tid  = threadIdx.x;
    const int d    = tid & 127;
    const int half = tid >> 7;

    __shared__ float s_co[64];
    __shared__ float s_red[256];

    if (tid < i1 - i0) s_co[tid] = coeff[(size_t)bh * 512 + i0 + tid];
    __syncthreads();

    const float* vnew = qkv + (size_t)(8 + b) * 4096 + h * HD;

    float acc = 0.0f;
    for (int i = i0 + half; i < i1; i += 2) {
        const int s = (i < NS) ? i : (PAST - RB + (i - NS));
        const float* vr = (s < PAST)
            ? (pv + ((size_t)bh * PAST + s) * HD)
            : vnew;
        acc += s_co[i - i0] * vr[d];
    }
    s_red[tid] = acc;
    __syncthreads();
    if (tid < 128)
        partial[((size_t)bh * 8 + blockIdx.x) * HD + d] = s_red[tid] + s_red[tid + 128];
}

// ---------------- Attention phase 4: reduce partials ----------------
__global__ __launch_bounds__(256) void reduce_kernel(
    const float* __restrict__ partial,  // [128][8][128]
    float* __restrict__ attn_out)       // [4][4096] == [128][128]
{
    const int idx = blockIdx.x * 256 + threadIdx.x;   // bh*128 + d
    const int bh = idx >> 7;
    const int d  = idx & 127;
    float s = 0.0f;
#pragma unroll
    for (int c = 0; c < 8; ++c)
        s += partial[(size_t)bh * 1024 + c * 128 + d];
    attn_out[idx] = s;
}

extern "C" void kernel_launch(void* const* d_in, const int* in_sizes, int n_in,
                              void* d_out, int out_size, void* d_ws, size_t ws_size,
                              hipStream_t stream)
{
    const float* hs = (const float*)d_in[0];
    const float* pk = (const float*)d_in[1];
    const float* pv = (const float*)d_in[2];
    const float* am = (const float*)d_in[3];
    const float* cm = (const float*)d_in[4];
    const float* ps = (const float*)d_in[5];
    const float* Wq = (const float*)d_in[6];
    const float* bq = (const float*)d_in[7];
    const float* Wk = (const float*)d_in[8];
    const float* bk = (const float*)d_in[9];
    const float* Wv = (const float*)d_in[10];
    const float* bv = (const float*)d_in[11];
    const float* Wo = (const float*)d_in[12];
    const float* bo = (const float*)d_in[13];
    const int*   sb = (const int*)d_in[14];
    const int*   rb = (const int*)d_in[15];

    float* qkv  = (float*)d_ws;                 // 49152
    float* aout = qkv + 3 * 4 * 4096;           // 16384
    float* sc   = aout + 4 * 4096;              // 128*512 = 65536
    float* part = sc + 128 * 512;               // 128*8*128 = 131072
    float* out  = (float*)d_out;

    const float scaling = 0.08838834764831845f;  // 128^-0.5

    gemv_kernel<3><<<768, 256, 0, stream>>>(hs, Wq, bq, Wk, bk, Wv, bv, scaling, qkv);
    score_kernel<<<dim3(16, 128), 256, 0, stream>>>(qkv, pk, am, cm, sb, rb, sc);
    softmax_kernel<<<128, 256, 0, stream>>>(ps, sb, rb, sc);
    pv_kernel<<<dim3(8, 128), 256, 0, stream>>>(qkv, pv, sc, sb, rb, part);
    reduce_kernel<<<64, 256, 0, stream>>>(part, aout);
    gemv_kernel<1><<<256, 256, 0, stream>>>(aout, Wo, bo, Wo, bo, Wo, bo, 1.0f, out);
}

// Round 3
// 102.118 us; speedup vs baseline: 2.9198x; 1.5017x over previous
//
#include <hip/hip_runtime.h>
#include <cstdint>
#include <cstddef>

#define FMIN_F (-3.402823466e38f)

__device__ __forceinline__ float wave_sum(float v) {
#pragma unroll
    for (int off = 32; off > 0; off >>= 1)
        v += __shfl_down(v, off, 64);
    return v; // valid in lane 0
}

// ---------------- GEMV ----------------
// Each wave computes 2 consecutive rows for all 4 batches.
// Block = 256 threads = 4 waves = 8 rows. Grid = NMAT*4096/8 blocks.
// launch_bounds(256,6): cap VGPR ~85 so 6 waves/SIMD stay resident
// (R2 version had VGPR=256 -> 10% occupancy -> 1 TB/s, latency-bound).
template <int NMAT>
__global__ __launch_bounds__(256, 6) void gemv_kernel(
    const float* __restrict__ X,                                  // [4][4096]
    const float* __restrict__ W0, const float* __restrict__ B0,
    const float* __restrict__ W1, const float* __restrict__ B1,
    const float* __restrict__ W2, const float* __restrict__ B2,
    float scale0,
    float* __restrict__ Y)                                        // [NMAT][4][4096]
{
    const int wave = threadIdx.x >> 6;
    const int lane = threadIdx.x & 63;
    const int rid  = blockIdx.x * 8 + wave * 2;        // first of 2 rows
    const int mi   = (NMAT == 1) ? 0 : (rid >> 12);
    const int r    = rid & 4095;

    const float* W  = (mi == 0) ? W0 : (mi == 1) ? W1 : W2;
    const float* Bs = (mi == 0) ? B0 : (mi == 1) ? B1 : B2;
    const float4* Wa = (const float4*)W + (size_t)r * 1024;
    const float4* Wb = Wa + 1024;
    const float4* X4 = (const float4*)X;

    float acc[2][4] = {{0.f, 0.f, 0.f, 0.f}, {0.f, 0.f, 0.f, 0.f}};
#pragma unroll 2
    for (int it = 0; it < 16; ++it) {
        const int idx = it * 64 + lane;
        const float4 wa = Wa[idx];
        const float4 wb = Wb[idx];
        const float4 x0 = X4[idx];
        const float4 x1 = X4[1024 + idx];
        const float4 x2 = X4[2048 + idx];
        const float4 x3 = X4[3072 + idx];
        acc[0][0] += wa.x * x0.x + wa.y * x0.y + wa.z * x0.z + wa.w * x0.w;
        acc[0][1] += wa.x * x1.x + wa.y * x1.y + wa.z * x1.z + wa.w * x1.w;
        acc[0][2] += wa.x * x2.x + wa.y * x2.y + wa.z * x2.z + wa.w * x2.w;
        acc[0][3] += wa.x * x3.x + wa.y * x3.y + wa.z * x3.z + wa.w * x3.w;
        acc[1][0] += wb.x * x0.x + wb.y * x0.y + wb.z * x0.z + wb.w * x0.w;
        acc[1][1] += wb.x * x1.x + wb.y * x1.y + wb.z * x1.z + wb.w * x1.w;
        acc[1][2] += wb.x * x2.x + wb.y * x2.y + wb.z * x2.z + wb.w * x2.w;
        acc[1][3] += wb.x * x3.x + wb.y * x3.y + wb.z * x3.z + wb.w * x3.w;
    }
#pragma unroll
    for (int j = 0; j < 2; ++j) {
#pragma unroll
        for (int b = 0; b < 4; ++b) {
            float v = wave_sum(acc[j][b]);
            if (lane == 0) {
                float o = v + Bs[r + j];
                if (mi == 0) o *= scale0;
                Y[((size_t)(mi * 4 + b)) * 4096 + (r + j)] = o;
            }
        }
    }
}

// ---------------- Attention phase 1: scores ----------------
__global__ __launch_bounds__(256) void score_kernel(
    const float* __restrict__ qkv,     // [3][4][4096]
    const float* __restrict__ pk,      // [B,H,2048,128]
    const float* __restrict__ amask,   // [B,1,1,2049]
    const float* __restrict__ cam,     // [B*H,1,2049]
    const int* __restrict__ sbp, const int* __restrict__ rbp,
    float* __restrict__ scores)        // [128][512]
{
    constexpr int PAST = 2048, S = 2049, HD = 128;
    const int bh = blockIdx.y;
    const int b  = bh >> 5;
    const int h  = bh & 31;
    const int SB = sbp[0], RB = rbp[0];
    const int NS = SB + 1;
    const int NA = NS + RB + 1;

    const int wave = threadIdx.x >> 6;
    const int lane = threadIdx.x & 63;

    const float* qh   = qkv + (size_t)b * 4096 + h * HD;
    const float* knew = qkv + (size_t)(4 + b) * 4096 + h * HD;
    const float2 ql = ((const float2*)qh)[lane];

#pragma unroll
    for (int j = 0; j < 8; ++j) {
        const int i = blockIdx.x * 32 + j * 4 + wave;
        if (i >= NA) continue;
        const int s = (i < NS) ? i : (PAST - RB + (i - NS));
        const float2* kr = (s < PAST)
            ? (const float2*)(pk + ((size_t)bh * PAST + s) * HD)
            : (const float2*)knew;
        const float2 kk = kr[lane];
        float p = ql.x * kk.x + ql.y * kk.y;
        p = wave_sum(p);
        if (lane == 0) {
            const float m  = cam[(size_t)bh * S + s];
            float sc = fmaxf(p + amask[(size_t)b * S + s], FMIN_F);
            sc = sc * m + (1.0f - m) * FMIN_F;
            scores[(size_t)bh * 512 + i] = sc;
        }
    }
}

// ---------------- Attention phase 2: softmax + coefficient fixups ----------------
__global__ __launch_bounds__(256) void softmax_kernel(
    const float* __restrict__ ps,      // [B*H,2048]
    const int* __restrict__ sbp, const int* __restrict__ rbp,
    float* __restrict__ scores)        // [128][512] in/out
{
    constexpr int PAST = 2048;
    const int bh = blockIdx.x;
    const int SB = sbp[0], RB = rbp[0];
    const int NS = SB + 1;
    const int NA = NS + RB + 1;
    const int tid = threadIdx.x;

    __shared__ float s_c[512];
    __shared__ float s_red[256];
    __shared__ float s_mm;

    for (int i = tid; i < NA; i += 256) s_c[i] = scores[(size_t)bh * 512 + i];

    {
        float part = 0.0f;
        const int cnt = SB + RB;
        for (int i = tid; i < cnt; i += 256) {
            const int idx = (i < SB) ? i : (PAST - RB + (i - SB));
            part += ps[(size_t)bh * PAST + idx];
        }
        s_red[tid] = part;
    }
    __syncthreads();
#pragma unroll
    for (int st = 128; st > 0; st >>= 1) {
        if (tid < st) s_red[tid] += s_red[tid + st];
        __syncthreads();
    }
    if (tid == 0) {
        const float mean = s_red[0] / (float)(SB + RB);
        const float prob = ps[(size_t)bh * PAST + (PAST - RB)] / mean;
        s_mm = (prob > 1.0f) ? (1.0f / 32.0f) : 0.0f;
    }
    __syncthreads();

    float mx = -INFINITY;
    for (int i = tid; i < NA; i += 256) mx = fmaxf(mx, s_c[i]);
    s_red[tid] = mx;
    __syncthreads();
#pragma unroll
    for (int st = 128; st > 0; st >>= 1) {
        if (tid < st) s_red[tid] = fmaxf(s_red[tid], s_red[tid + st]);
        __syncthreads();
    }
    const float gmax = s_red[0];
    __syncthreads();

    float lsum = 0.0f;
    for (int i = tid; i < NA; i += 256) {
        const float e = expf(s_c[i] - gmax);
        s_c[i] = e;
        lsum += e;
    }
    s_red[tid] = lsum;
    __syncthreads();
#pragma unroll
    for (int st = 128; st > 0; st >>= 1) {
        if (tid < st) s_red[tid] += s_red[tid + st];
        __syncthreads();
    }
    const float inv = 1.0f / s_red[0];
    __syncthreads();
    for (int i = tid; i < NA; i += 256) s_c[i] *= inv;
    __syncthreads();

    if (tid == 0) {
        float sm = 0.0f;
#pragma unroll
        for (int j = 1; j <= 32; ++j) sm += s_c[NS + j];
        s_c[NS] += s_mm * sm;       // folded CAM value-merge
        s_c[SB]  = 0.99f;           // pinned col * 0.99 value scale
    }
    __syncthreads();

    for (int i = tid; i < NA; i += 256) scores[(size_t)bh * 512 + i] = s_c[i];
}

// ---------------- Attention phase 3: PV partials ----------------
__global__ __launch_bounds__(256) void pv_kernel(
    const float* __restrict__ qkv,     // for v_new
    const float* __restrict__ pv,      // [B,H,2048,128]
    const float* __restrict__ coeff,   // [128][512]
    const int* __restrict__ sbp, const int* __restrict__ rbp,
    float* __restrict__ partial)       // [128][8][128]
{
    constexpr int PAST = 2048, HD = 128;
    const int bh = blockIdx.y;
    const int b  = bh >> 5;
    const int h  = bh & 31;
    const int SB = sbp[0], RB = rbp[0];
    const int NS = SB + 1;
    const int NA = NS + RB + 1;
    const int CPC = (NA + 7) >> 3;
    const int i0 = blockIdx.x * CPC;
    const int i1 = min(NA, i0 + CPC);

    const int tid  = threadIdx.x;
    const int d    = tid & 127;
    const int half = tid >> 7;

    __shared__ float s_co[64];
    __shared__ float s_red[256];

    if (tid < i1 - i0) s_co[tid] = coeff[(size_t)bh * 512 + i0 + tid];
    __syncthreads();

    const float* vnew = qkv + (size_t)(8 + b) * 4096 + h * HD;

    float acc = 0.0f;
    for (int i = i0 + half; i < i1; i += 2) {
        const int s = (i < NS) ? i : (PAST - RB + (i - NS));
        const float* vr = (s < PAST)
            ? (pv + ((size_t)bh * PAST + s) * HD)
            : vnew;
        acc += s_co[i - i0] * vr[d];
    }
    s_red[tid] = acc;
    __syncthreads();
    if (tid < 128)
        partial[((size_t)bh * 8 + blockIdx.x) * HD + d] = s_red[tid] + s_red[tid + 128];
}

// ---------------- Attention phase 4: reduce partials ----------------
__global__ __launch_bounds__(256) void reduce_kernel(
    const float* __restrict__ partial,  // [128][8][128]
    float* __restrict__ attn_out)       // [4][4096] == [128][128]
{
    const int idx = blockIdx.x * 256 + threadIdx.x;
    const int bh = idx >> 7;
    const int d  = idx & 127;
    float s = 0.0f;
#pragma unroll
    for (int c = 0; c < 8; ++c)
        s += partial[(size_t)bh * 1024 + c * 128 + d];
    attn_out[idx] = s;
}

extern "C" void kernel_launch(void* const* d_in, const int* in_sizes, int n_in,
                              void* d_out, int out_size, void* d_ws, size_t ws_size,
                              hipStream_t stream)
{
    const float* hs = (const float*)d_in[0];
    const float* pk = (const float*)d_in[1];
    const float* pv = (const float*)d_in[2];
    const float* am = (const float*)d_in[3];
    const float* cm = (const float*)d_in[4];
    const float* ps = (const float*)d_in[5];
    const float* Wq = (const float*)d_in[6];
    const float* bq = (const float*)d_in[7];
    const float* Wk = (const float*)d_in[8];
    const float* bk = (const float*)d_in[9];
    const float* Wv = (const float*)d_in[10];
    const float* bv = (const float*)d_in[11];
    const float* Wo = (const float*)d_in[12];
    const float* bo = (const float*)d_in[13];
    const int*   sb = (const int*)d_in[14];
    const int*   rb = (const int*)d_in[15];

    float* qkv  = (float*)d_ws;                 // 49152
    float* aout = qkv + 3 * 4 * 4096;           // 16384
    float* sc   = aout + 4 * 4096;              // 65536
    float* part = sc + 128 * 512;               // 131072
    float* out  = (float*)d_out;

    const float scaling = 0.08838834764831845f;  // 128^-0.5

    gemv_kernel<3><<<1536, 256, 0, stream>>>(hs, Wq, bq, Wk, bk, Wv, bv, scaling, qkv);
    score_kernel<<<dim3(16, 128), 256, 0, stream>>>(qkv, pk, am, cm, sb, rb, sc);
    softmax_kernel<<<128, 256, 0, stream>>>(ps, sb, rb, sc);
    pv_kernel<<<dim3(8, 128), 256, 0, stream>>>(qkv, pv, sc, sb, rb, part);
    reduce_kernel<<<64, 256, 0, stream>>>(part, aout);
    gemv_kernel<1><<<512, 256, 0, stream>>>(aout, Wo, bo, Wo, bo, Wo, bo, 1.0f, out);
}